// Round 1
// baseline (4475.817 us; speedup 1.0000x reference)
//
#include <hip/hip_runtime.h>

typedef __attribute__((ext_vector_type(8))) short bf16x8;
typedef __attribute__((ext_vector_type(8))) unsigned short u16x8;
typedef __attribute__((ext_vector_type(4))) float f32x4;

__device__ __forceinline__ unsigned short f2bf(float f){
    unsigned int u = __builtin_bit_cast(unsigned int, f);
    u += 0x7fffu + ((u >> 16) & 1u);
    return (unsigned short)(u >> 16);
}
__device__ __forceinline__ float bf2f(unsigned short h){
    unsigned int u = ((unsigned int)h) << 16;
    return __builtin_bit_cast(float, u);
}
__device__ __forceinline__ f32x4 mfma16(bf16x8 a, bf16x8 b, f32x4 c){
    return __builtin_amdgcn_mfma_f32_16x16x32_bf16(a, b, c, 0, 0, 0);
}

// ---------------- x fp32 -> bf16 ----------------
__global__ __launch_bounds__(256) void cvt_x_kernel(const float* __restrict__ x,
                                                    unsigned short* __restrict__ xb){
    size_t i = ((size_t)blockIdx.x * 256 + threadIdx.x) * 4;
    float4 f = *(const float4*)(x + i);
    ushort4 o;
    o.x = f2bf(f.x); o.y = f2bf(f.y); o.z = f2bf(f.z); o.w = f2bf(f.w);
    *(ushort4*)(xb + i) = o;
}

// ---------------- GEMM: C[M,Nv] = A[M,K](bf16) @ B[K,N](fp32, converted) ----------------
// EPI=0: Nv=20480 fused qkv (region 0: q->ws bf16, 1: k->out fp32, 2: v->out fp32 + ws bf16)
// EPI=1: Nv=8192  out = A @ Wo + bo (fp32)
template<int EPI>
__global__ __launch_bounds__(256) void gemm_kernel(
    const unsigned short* __restrict__ A, int K,
    const float* __restrict__ W0, const float* __restrict__ W1, const float* __restrict__ W2,
    const float* __restrict__ bias0, const float* __restrict__ bias1, const float* __restrict__ bias2,
    unsigned short* __restrict__ q_ws,
    float* __restrict__ k_out, float* __restrict__ v_out,
    unsigned short* __restrict__ v_ws,
    float* __restrict__ outp)
{
    __shared__ unsigned short Als[2][128][40];   // [row][k], pad 40 (even b128 bank spread)
    __shared__ unsigned short Bls[2][128][40];   // [n][k]

    const int t    = threadIdx.x;
    const int lane = t & 63;
    const int wid  = t >> 6;
    const int wr   = wid >> 1, wc = wid & 1;
    const int llo  = lane & 15, lhi = lane >> 4;

    // 16x16 supertile band ordering: ~256 in-flight blocks share 16 A-panels + 16 B-panels (L3-resident)
    const int bid  = blockIdx.x;
    const int band = bid >> 9;
    const int rem  = bid & 511;
    const int tm   = rem >> 4;
    const int tn   = (band << 4) + (rem & 15);

    const int brow = tm * 128;
    const int gn   = tn * 128;

    const float* Bp; const float* biasp; int ldb; int bcol; int region;
    if (EPI == 1)          { Bp = W0; biasp = bias0; ldb = 8192;  bcol = gn;         region = 3; }
    else if (gn < 16384)   { Bp = W0; biasp = bias0; ldb = 16384; bcol = gn;         region = 0; }
    else if (gn < 18432)   { Bp = W1; biasp = bias1; ldb = 2048;  bcol = gn - 16384; region = 1; }
    else                   { Bp = W2; biasp = bias2; ldb = 2048;  bcol = gn - 18432; region = 2; }

    const int arow = t >> 2;          // 0..63 (+64 for second half)
    const int ak8  = (t & 3) * 8;     // 0,8,16,24
    const int bn   = t & 127;         // 0..127
    const int kb   = (t >> 7) * 16;   // 0 or 16

    const unsigned short* aptr = A + (size_t)(brow + arow) * K + ak8;
    const float*          bptr = Bp + (size_t)kb * ldb + bcol + bn;

    int4 areg0, areg1;
    float breg[16];

    auto load_tile = [&](int ks){
        const unsigned short* ap = aptr + ks * 32;
        areg0 = *(const int4*)ap;
        areg1 = *(const int4*)(ap + (size_t)64 * K);
        const float* bp = bptr + (size_t)ks * 32 * ldb;
        #pragma unroll
        for (int j = 0; j < 16; ++j) breg[j] = bp[(size_t)j * ldb];
    };
    auto store_tile = [&](int buf){
        *(int4*)&Als[buf][arow][ak8]      = areg0;
        *(int4*)&Als[buf][arow + 64][ak8] = areg1;
        u16x8 w0, w1;
        #pragma unroll
        for (int j = 0; j < 8; ++j){ w0[j] = f2bf(breg[j]); w1[j] = f2bf(breg[j + 8]); }
        *(u16x8*)&Bls[buf][bn][kb]     = w0;
        *(u16x8*)&Bls[buf][bn][kb + 8] = w1;
    };

    const f32x4 zero = {0.f, 0.f, 0.f, 0.f};
    f32x4 acc[4][4];
    #pragma unroll
    for (int i = 0; i < 4; ++i)
        #pragma unroll
        for (int j = 0; j < 4; ++j) acc[i][j] = zero;

    const int NS = K >> 5;
    load_tile(0);
    store_tile(0);
    __syncthreads();

    for (int ks = 0; ks < NS; ++ks){
        const int cur = ks & 1;
        if (ks + 1 < NS) load_tile(ks + 1);
        bf16x8 af[4], bfr[4];
        #pragma unroll
        for (int mi = 0; mi < 4; ++mi)
            af[mi] = *(const bf16x8*)&Als[cur][wr*64 + mi*16 + llo][lhi*8];
        #pragma unroll
        for (int ni = 0; ni < 4; ++ni)
            bfr[ni] = *(const bf16x8*)&Bls[cur][wc*64 + ni*16 + llo][lhi*8];
        #pragma unroll
        for (int mi = 0; mi < 4; ++mi)
            #pragma unroll
            for (int ni = 0; ni < 4; ++ni)
                acc[mi][ni] = mfma16(af[mi], bfr[ni], acc[mi][ni]);
        if (ks + 1 < NS) store_tile((ks + 1) & 1);
        __syncthreads();
    }

    // epilogue: C/D layout col=lane&15, row=(lane>>4)*4+r
    #pragma unroll
    for (int mi = 0; mi < 4; ++mi){
        #pragma unroll
        for (int ni = 0; ni < 4; ++ni){
            const int col  = bcol + wc*64 + ni*16 + llo;
            const float bv = biasp[col];
            const int row0 = brow + wr*64 + mi*16 + lhi*4;
            #pragma unroll
            for (int r = 0; r < 4; ++r){
                const float val = acc[mi][ni][r] + bv;
                const size_t rr = (size_t)(row0 + r);
                if (EPI == 1){
                    outp[rr * 8192 + col] = val;
                } else if (region == 0){
                    q_ws[rr * 16384 + col] = f2bf(val);
                } else if (region == 1){
                    k_out[rr * 2048 + col] = val;
                } else {
                    v_out[rr * 2048 + col] = val;
                    v_ws[rr * 2048 + col]  = f2bf(val);
                }
            }
        }
    }
}

// ---------------- RoPE (pair i, i+64 per thread; NeoX rotate-halves) ----------------
__global__ __launch_bounds__(256) void rope_q_kernel(unsigned short* __restrict__ q){
    const size_t idx = (size_t)blockIdx.x * 256 + threadIdx.x;   // 33,554,432 pairs
    const int i = (int)(idx & 63);
    const int h = (int)((idx >> 6) & 127);
    const int r = (int)(idx >> 13);
    const int s = r & 2047;
    const float inv = exp2f(-(float)i * 0.20762050593046014f);   // log2(10000)/64
    float c, sn;
    sincosf((float)s * inv, &sn, &c);
    unsigned short* p = q + (size_t)r * 16384 + h * 128 + i;
    const float v1 = bf2f(p[0]);
    const float v2 = bf2f(p[64]);
    p[0]  = f2bf(v1 * c - v2 * sn);
    p[64] = f2bf(v2 * c + v1 * sn);
}

__global__ __launch_bounds__(256) void rope_k_kernel(float* __restrict__ kio,
                                                     unsigned short* __restrict__ kws){
    const size_t idx = (size_t)blockIdx.x * 256 + threadIdx.x;   // 4,194,304 pairs
    const int i = (int)(idx & 63);
    const int h = (int)((idx >> 6) & 15);
    const int r = (int)(idx >> 10);
    const int s = r & 2047;
    const float inv = exp2f(-(float)i * 0.20762050593046014f);
    float c, sn;
    sincosf((float)s * inv, &sn, &c);
    float* p = kio + (size_t)r * 2048 + h * 128 + i;
    const float v1 = p[0], v2 = p[64];
    const float o1 = v1 * c - v2 * sn;
    const float o2 = v2 * c + v1 * sn;
    p[0] = o1; p[64] = o2;
    unsigned short* pw = kws + (size_t)r * 2048 + h * 128 + i;
    pw[0]  = f2bf(o1);
    pw[64] = f2bf(o2);
}

// ---------------- block-local GQA attention ----------------
// block = (b, blk, hkv, g, qhalf): 64 q-rows, 4 waves x 16 rows, KV block 128x128
__global__ __launch_bounds__(256) void attn_kernel(
    const unsigned short* __restrict__ q,
    const unsigned short* __restrict__ kbf,
    const unsigned short* __restrict__ vbf,
    unsigned short* __restrict__ ao)
{
    __shared__ unsigned short KV[128][136];       // K, then reused as V^T
    __shared__ unsigned short Pls[4][16][136];

    const int t    = threadIdx.x;
    const int lane = t & 63;
    const int wid  = t >> 6;
    const int llo  = lane & 15, lhi = lane >> 4;

    const int bid = blockIdx.x;            // 8192 = b(1) blk(4) hkv(4) g(3) qh(1) bits
    const int qh  = bid & 1;
    const int g   = (bid >> 1) & 7;
    const int hkv = (bid >> 4) & 15;
    const int blk = (bid >> 8) & 15;
    const int b   = bid >> 12;

    const int h     = hkv * 8 + g;
    const int sbase = b * 2048 + blk * 128;
    const int qbase = sbase + qh * 64 + wid * 16;

    // stage K: [j][d]
    {
        const int row = t >> 1;
        const int d0  = (t & 1) * 64;
        const unsigned short* src = kbf + (size_t)(sbase + row) * 2048 + hkv * 128 + d0;
        #pragma unroll
        for (int i2 = 0; i2 < 8; ++i2)
            *(int4*)&KV[row][d0 + i2*8] = *(const int4*)(src + i2*8);
    }

    // Q frags from global (row = qbase+llo, k = kc*32 + lhi*8)
    bf16x8 qf[4];
    {
        const unsigned short* qp = q + (size_t)(qbase + llo) * 16384 + h * 128 + lhi * 8;
        #pragma unroll
        for (int kc = 0; kc < 4; ++kc)
            qf[kc] = *(const bf16x8*)(qp + kc * 32);
    }

    __syncthreads();

    // scores S[i][j], i = wave-local q-row, j = kv-row
    const f32x4 zero = {0.f,0.f,0.f,0.f};
    f32x4 sc[8];
    #pragma unroll
    for (int ni = 0; ni < 8; ++ni) sc[ni] = zero;
    #pragma unroll
    for (int kc = 0; kc < 4; ++kc){
        #pragma unroll
        for (int ni = 0; ni < 8; ++ni){
            bf16x8 kf = *(const bf16x8*)&KV[ni*16 + llo][kc*32 + lhi*8];
            sc[ni] = mfma16(qf[kc], kf, sc[ni]);
        }
    }

    // softmax over j (128): local max over ni, then shfl_xor across the 16 column-lanes
    const float scale = 0.08838834764831845f;
    #pragma unroll
    for (int r = 0; r < 4; ++r){
        float m = sc[0][r];
        #pragma unroll
        for (int ni = 1; ni < 8; ++ni) m = fmaxf(m, sc[ni][r]);
        #pragma unroll
        for (int off = 1; off < 16; off <<= 1) m = fmaxf(m, __shfl_xor(m, off));
        float sum = 0.f;
        #pragma unroll
        for (int ni = 0; ni < 8; ++ni){
            const float p = __expf((sc[ni][r] - m) * scale);
            sc[ni][r] = p; sum += p;
        }
        #pragma unroll
        for (int off = 1; off < 16; off <<= 1) sum += __shfl_xor(sum, off);
        const float rs = 1.f / sum;
        #pragma unroll
        for (int ni = 0; ni < 8; ++ni) sc[ni][r] *= rs;
    }

    // P -> LDS (own-wave region)
    #pragma unroll
    for (int ni = 0; ni < 8; ++ni)
        #pragma unroll
        for (int r = 0; r < 4; ++r)
            Pls[wid][lhi*4 + r][ni*16 + llo] = f2bf(sc[ni][r]);

    __syncthreads();   // all waves done reading K

    // stage V^T into KV: [d][j]
    {
        const int d  = t & 127;
        const int j0 = (t >> 7) * 64;
        const unsigned short* vs = vbf + (size_t)sbase * 2048 + hkv * 128 + d;
        #pragma unroll
        for (int jj = 0; jj < 64; jj += 8){
            u16x8 pk;
            #pragma unroll
            for (int e = 0; e < 8; ++e)
                pk[e] = vs[(size_t)(j0 + jj + e) * 2048];
            *(u16x8*)&KV[d][j0 + jj] = pk;
        }
    }

    __syncthreads();

    // PV: out[i][d] = sum_j P[i][j] V[j][d];  A=P[i][j], B=V^T[d][j]
    f32x4 oc[8];
    #pragma unroll
    for (int ni = 0; ni < 8; ++ni) oc[ni] = zero;
    #pragma unroll
    for (int kc = 0; kc < 4; ++kc){
        bf16x8 pf = *(const bf16x8*)&Pls[wid][llo][kc*32 + lhi*8];
        #pragma unroll
        for (int ni = 0; ni < 8; ++ni){
            bf16x8 vf = *(const bf16x8*)&KV[ni*16 + llo][kc*32 + lhi*8];
            oc[ni] = mfma16(pf, vf, oc[ni]);
        }
    }

    #pragma unroll
    for (int ni = 0; ni < 8; ++ni){
        #pragma unroll
        for (int r = 0; r < 4; ++r){
            const size_t row = (size_t)(qbase + lhi*4 + r);
            ao[row * 16384 + h*128 + ni*16 + llo] = f2bf(oc[ni][r]);
        }
    }
}

// ---------------- launch ----------------
extern "C" void kernel_launch(void* const* d_in, const int* in_sizes, int n_in,
                              void* d_out, int out_size, void* d_ws, size_t ws_size,
                              hipStream_t stream)
{
    const float* x  = (const float*)d_in[0];
    const float* Wq = (const float*)d_in[1];
    const float* bq = (const float*)d_in[2];
    const float* Wk = (const float*)d_in[3];
    const float* bk = (const float*)d_in[4];
    const float* Wv = (const float*)d_in[5];
    const float* bv = (const float*)d_in[6];
    const float* Wo = (const float*)d_in[7];
    const float* bo = (const float*)d_in[8];

    float* outp  = (float*)d_out;                       // (B,S,E) = 33,554,432
    float* k_out = outp + (size_t)33554432;             // (B,S,HKV,D) = 8,388,608
    float* v_out = outp + (size_t)41943040;             // (B,S,HKV,D)

    char* w = (char*)d_ws;
    unsigned short* xb  = (unsigned short*)(w);                    //  64 MB x bf16
    unsigned short* qb  = (unsigned short*)(w + 67108864ull);      // 128 MB q bf16 (roped in place)
    unsigned short* kb2 = (unsigned short*)(w + 201326592ull);     //  16 MB k bf16 roped
    unsigned short* vb2 = (unsigned short*)(w + 218103808ull);     //  16 MB v bf16
    unsigned short* aob = (unsigned short*)(w + 234881024ull);     // 128 MB attn_out bf16

    cvt_x_kernel<<<32768, 256, 0, stream>>>(x, xb);
    gemm_kernel<0><<<5120, 256, 0, stream>>>(xb, 8192, Wq, Wk, Wv, bq, bk, bv,
                                             qb, k_out, v_out, vb2, nullptr);
    rope_q_kernel<<<131072, 256, 0, stream>>>(qb);
    rope_k_kernel<<<16384, 256, 0, stream>>>(k_out, kb2);
    attn_kernel<<<8192, 256, 0, stream>>>(qb, kb2, vb2, aob);
    gemm_kernel<1><<<2048, 256, 0, stream>>>(aob, 16384, Wo, nullptr, nullptr, bo, nullptr, nullptr,
                                             nullptr, nullptr, nullptr, nullptr, outp);
}